// Round 1
// baseline (641.490 us; speedup 1.0000x reference)
//
#include <hip/hip_runtime.h>
#include <hip/hip_bf16.h>

// Problem constants (ResNet-50 CBP head)
#define BATCH 8
#define CH    2048
#define LSP   784          // H*W = 28*28
#define KPAD  800          // pad K to 25*32 for MFMA k-steps
#define KSTEPS (KPAD/32)   // 25
#define DDIM  8192         // count-sketch dim (power of 2)
#define NCLS  200

typedef __bf16 bf16x8 __attribute__((ext_vector_type(8)));
typedef float  f32x4  __attribute__((ext_vector_type(4)));

// fp32 -> bf16 round-to-nearest-even (bit pattern)
__device__ __forceinline__ unsigned short f2bf_rn(float f) {
    unsigned int u = __float_as_uint(f);
    unsigned int r = u + 0x7fffu + ((u >> 16) & 1u);
    return (unsigned short)(r >> 16);
}

// ---------------------------------------------------------------------------
// Kernel 1: split x (fp32, [B,C,784]) into hi/lo bf16 [B,C,KPAD] (zero-pad K)
// ---------------------------------------------------------------------------
__global__ __launch_bounds__(256) void split_kernel(
    const float* __restrict__ x,
    unsigned short* __restrict__ xhi,
    unsigned short* __restrict__ xlo)
{
    int idx = blockIdx.x * 256 + threadIdx.x;
    if (idx >= BATCH * CH * KPAD) return;
    int l  = idx % KPAD;
    int bc = idx / KPAD;
    float v = (l < LSP) ? x[(size_t)bc * LSP + l] : 0.0f;
    unsigned short hu = f2bf_rn(v);
    float hf = __uint_as_float(((unsigned int)hu) << 16);
    unsigned short lu = f2bf_rn(v - hf);   // x - hi is exact in fp32
    xhi[idx] = hu;
    xlo[idx] = lu;
}

// ---------------------------------------------------------------------------
// Kernel 2: fused Gram (bf16-split MFMA) + count-sketch scatter into LDS bins
// grid = (4 tileN-groups, 16 tileM, 8 batch), 256 threads (4 waves)
// Each block: 128 (M) x 512 (N, 4 tiles sequentially) Gram region, K=800.
// ---------------------------------------------------------------------------
__device__ __forceinline__ void stage_tile(
    const unsigned short* __restrict__ src, size_t rowbase_elems,
    unsigned short* lds_tile, int wv, int lane, int k0)
{
#pragma unroll
    for (int half = 0; half < 2; ++half) {
        int ch = wv * 2 + half;                       // 0..7 chunk of the 8KB tile
        const unsigned short* g = src + rowbase_elems
            + (size_t)(ch * 16 + (lane >> 2)) * KPAD  // row in tile
            + k0 + (lane & 3) * 8;                    // 16B per lane along k
        // HW semantics: LDS dest = wave-uniform base + lane*16
        __builtin_amdgcn_global_load_lds(
            (__attribute__((address_space(1))) void*)g,
            (__attribute__((address_space(3))) void*)(lds_tile + ch * 512),
            16, 0, 0);
    }
}

__global__ __launch_bounds__(256) void gram_scatter_kernel(
    const unsigned short* __restrict__ xhi,
    const unsigned short* __restrict__ xlo,
    const int*   __restrict__ h1, const float* __restrict__ s1,
    const int*   __restrict__ h2, const float* __restrict__ s2,
    float* __restrict__ y)
{
    __shared__ __align__(16) unsigned short smA_hi[128 * 32];
    __shared__ __align__(16) unsigned short smA_lo[128 * 32];
    __shared__ __align__(16) unsigned short smB_hi[128 * 32];
    __shared__ __align__(16) unsigned short smB_lo[128 * 32];
    __shared__ float bins[DDIM];                      // 32 KB private histogram

    const int tid  = threadIdx.x;
    const int lane = tid & 63;
    const int wv   = tid >> 6;
    const int b    = blockIdx.z;
    const int tM   = blockIdx.y;
    const int tgN  = blockIdx.x;

    for (int i = tid; i < DDIM; i += 256) bins[i] = 0.0f;
    // (first __syncthreads inside k-loop orders this before any scatter)

    const int wrow = (wv >> 1) * 64;   // wave's 64x64 subtile origin
    const int wcol = (wv & 1) * 64;

    const size_t rowbaseA = ((size_t)b * CH + (size_t)tM * 128) * KPAD;

    for (int tni = 0; tni < 4; ++tni) {
        const int tN = tgN * 4 + tni;
        const size_t rowbaseB = ((size_t)b * CH + (size_t)tN * 128) * KPAD;

        f32x4 acc[4][4];
        const f32x4 zv = {0.0f, 0.0f, 0.0f, 0.0f};
#pragma unroll
        for (int mi = 0; mi < 4; ++mi)
#pragma unroll
            for (int ni = 0; ni < 4; ++ni) acc[mi][ni] = zv;

        for (int ks = 0; ks < KSTEPS; ++ks) {
            const int k0 = ks * 32;
            stage_tile(xhi, rowbaseA, smA_hi, wv, lane, k0);
            stage_tile(xlo, rowbaseA, smA_lo, wv, lane, k0);
            stage_tile(xhi, rowbaseB, smB_hi, wv, lane, k0);
            stage_tile(xlo, rowbaseB, smB_lo, wv, lane, k0);
            __syncthreads();

            bf16x8 ah[4], al[4], bh[4], bl[4];
#pragma unroll
            for (int i = 0; i < 4; ++i) {
                int offa = (wrow + i * 16 + (lane & 15)) * 32 + (lane >> 4) * 8;
                ah[i] = *(const bf16x8*)&smA_hi[offa];
                al[i] = *(const bf16x8*)&smA_lo[offa];
                int offb = (wcol + i * 16 + (lane & 15)) * 32 + (lane >> 4) * 8;
                bh[i] = *(const bf16x8*)&smB_hi[offb];
                bl[i] = *(const bf16x8*)&smB_lo[offb];
            }
#pragma unroll
            for (int mi = 0; mi < 4; ++mi)
#pragma unroll
                for (int ni = 0; ni < 4; ++ni) {
                    acc[mi][ni] = __builtin_amdgcn_mfma_f32_16x16x32_bf16(ah[mi], bh[ni], acc[mi][ni], 0, 0, 0);
                    acc[mi][ni] = __builtin_amdgcn_mfma_f32_16x16x32_bf16(ah[mi], bl[ni], acc[mi][ni], 0, 0, 0);
                    acc[mi][ni] = __builtin_amdgcn_mfma_f32_16x16x32_bf16(al[mi], bh[ni], acc[mi][ni], 0, 0, 0);
                }
            __syncthreads();
        }

        // Scatter this 128x128 Gram tile into the LDS histogram.
        // C/D layout (m89-verified): col = lane&15, row = (lane>>4)*4 + reg
        const int c2b = tN * 128 + wcol + (lane & 15);
        const int c1b = tM * 128 + wrow + ((lane >> 4) << 2);
        int   hh2[4]; float ss2[4];
#pragma unroll
        for (int ni = 0; ni < 4; ++ni) {
            hh2[ni] = h2[c2b + ni * 16];
            ss2[ni] = s2[c2b + ni * 16];
        }
#pragma unroll
        for (int mi = 0; mi < 4; ++mi) {
#pragma unroll
            for (int r = 0; r < 4; ++r) {
                const int c1 = c1b + mi * 16 + r;
                const int hv = h1[c1];
                const float sv = s1[c1];
#pragma unroll
                for (int ni = 0; ni < 4; ++ni) {
                    float g = acc[mi][ni][r];
                    int bin = (hv + hh2[ni]) & (DDIM - 1);
                    atomicAdd(&bins[bin], sv * ss2[ni] * g);
                }
            }
        }
        // No barrier needed here: next iteration's staging touches only the
        // tile buffers (not bins), and barrier counts stay uniform.
    }

    __syncthreads();   // all scatters into bins complete
    float* yb = y + (size_t)b * DDIM;
    for (int i = tid; i < DDIM; i += 256) {
        float v = bins[i];
        if (v != 0.0f) atomicAdd(&yb[i], v);
    }
}

// ---------------------------------------------------------------------------
// Kernel 3: feat = sign(y)*sqrt(|y|) / max(||.||2, 1e-12)   (one block per b)
// Note sum(feat_unnorm^2) == sum(|y|).
// ---------------------------------------------------------------------------
__global__ __launch_bounds__(256) void feat_kernel(
    const float* __restrict__ y, float* __restrict__ out)
{
    const int b = blockIdx.x;
    const int tid = threadIdx.x;
    __shared__ float red[256];
    float ss = 0.0f;
    for (int i = tid; i < DDIM; i += 256) ss += fabsf(y[(size_t)b * DDIM + i]);
    red[tid] = ss;
    __syncthreads();
    for (int s = 128; s > 0; s >>= 1) {
        if (tid < s) red[tid] += red[tid + s];
        __syncthreads();
    }
    const float inv = 1.0f / fmaxf(sqrtf(red[0]), 1e-12f);
    for (int i = tid; i < DDIM; i += 256) {
        float v = y[(size_t)b * DDIM + i];
        float t = copysignf(sqrtf(fabsf(v)), v);
        out[BATCH * NCLS + (size_t)b * DDIM + i] = t * inv;
    }
}

// ---------------------------------------------------------------------------
// Kernel 4: logit[b,n] = feat[b,:] @ W[:,n] + b_cls[n]   (grid 200 x 8)
// ---------------------------------------------------------------------------
__global__ __launch_bounds__(256) void logit_kernel(
    const float* __restrict__ feat_base, const float* __restrict__ W,
    const float* __restrict__ bc, float* __restrict__ logit)
{
    const int n = blockIdx.x;
    const int b = blockIdx.y;
    const int tid = threadIdx.x;
    const float* feat = feat_base + (size_t)b * DDIM;
    float s = 0.0f;
    for (int d = tid; d < DDIM; d += 256) s += feat[d] * W[(size_t)d * NCLS + n];
    __shared__ float red[256];
    red[tid] = s;
    __syncthreads();
    for (int st = 128; st > 0; st >>= 1) {
        if (tid < st) red[tid] += red[tid + st];
        __syncthreads();
    }
    if (tid == 0) logit[(size_t)b * NCLS + n] = red[0] + bc[n];
}

// ---------------------------------------------------------------------------
extern "C" void kernel_launch(void* const* d_in, const int* in_sizes, int n_in,
                              void* d_out, int out_size, void* d_ws, size_t ws_size,
                              hipStream_t stream)
{
    const float* x  = (const float*)d_in[0];
    const float* s1 = (const float*)d_in[1];
    const float* s2 = (const float*)d_in[2];
    const float* W  = (const float*)d_in[3];
    const float* bc = (const float*)d_in[4];
    const int*   h1 = (const int*)d_in[5];
    const int*   h2 = (const int*)d_in[6];
    float* out = (float*)d_out;

    // workspace layout: y (256KB) | xhi (25MB) | xlo (25MB)  -> ~50.3 MB
    char* ws = (char*)d_ws;
    float* y = (float*)ws;
    const size_t ybytes = (size_t)BATCH * DDIM * sizeof(float);
    unsigned short* xhi = (unsigned short*)(ws + ybytes);
    unsigned short* xlo = (unsigned short*)(ws + ybytes + (size_t)BATCH * CH * KPAD * 2);

    hipMemsetAsync(y, 0, ybytes, stream);   // ws is re-poisoned before each call

    split_kernel<<<(BATCH * CH * KPAD + 255) / 256, 256, 0, stream>>>(x, xhi, xlo);

    dim3 grid_g(4, 16, BATCH);   // tileN-group, tileM, batch
    gram_scatter_kernel<<<grid_g, 256, 0, stream>>>(xhi, xlo, h1, s1, h2, s2, y);

    feat_kernel<<<BATCH, 256, 0, stream>>>(y, out);

    logit_kernel<<<dim3(NCLS, BATCH), 256, 0, stream>>>(out + BATCH * NCLS, W, bc, out);
}

// Round 2
// 489.505 us; speedup vs baseline: 1.3105x; 1.3105x over previous
//
#include <hip/hip_runtime.h>
#include <hip/hip_bf16.h>

// Problem constants (ResNet-50 CBP head)
#define BATCH 8
#define CH    2048
#define LSP   784          // H*W = 28*28
#define KPAD  800          // pad K to 25*32 for MFMA k-steps
#define KSTEPS (KPAD/32)   // 25
#define DDIM  8192         // count-sketch dim (power of 2)
#define NCLS  200
#define NTILE 16           // 2048/128 tiles per dim
#define NPAIR 136          // NTILE*(NTILE+1)/2 symmetric tile pairs

typedef __bf16 bf16x8 __attribute__((ext_vector_type(8)));
typedef float  f32x4  __attribute__((ext_vector_type(4)));

// fp32 -> bf16 round-to-nearest-even (bit pattern)
__device__ __forceinline__ unsigned short f2bf_rn(float f) {
    unsigned int u = __float_as_uint(f);
    unsigned int r = u + 0x7fffu + ((u >> 16) & 1u);
    return (unsigned short)(r >> 16);
}

// ---------------------------------------------------------------------------
// Kernel 1: split x (fp32, [B,C,784]) into hi/lo bf16 [B,C,KPAD], vec4
// ---------------------------------------------------------------------------
__global__ __launch_bounds__(256) void split_kernel(
    const float* __restrict__ x,
    unsigned short* __restrict__ xhi,
    unsigned short* __restrict__ xlo)
{
    int idx = blockIdx.x * 256 + threadIdx.x;          // vec4 index
    if (idx >= BATCH * CH * KPAD / 4) return;
    int v  = idx * 4;
    int bc = v / KPAD;
    int l  = v - bc * KPAD;                            // multiple of 4
    float4 xv = make_float4(0.f, 0.f, 0.f, 0.f);
    if (l < LSP)                                       // LSP%4==0: uniform per vec
        xv = *(const float4*)&x[(size_t)bc * LSP + l];
    ushort4 hv, lv;
    float f[4] = {xv.x, xv.y, xv.z, xv.w};
    unsigned short hu[4], lu[4];
#pragma unroll
    for (int i = 0; i < 4; ++i) {
        hu[i] = f2bf_rn(f[i]);
        float hf = __uint_as_float(((unsigned int)hu[i]) << 16);
        lu[i] = f2bf_rn(f[i] - hf);                    // residual, exact in fp32
    }
    hv.x = hu[0]; hv.y = hu[1]; hv.z = hu[2]; hv.w = hu[3];
    lv.x = lu[0]; lv.y = lu[1]; lv.z = lu[2]; lv.w = lu[3];
    *(ushort4*)&xhi[v] = hv;
    *(ushort4*)&xlo[v] = lv;
}

// ---------------------------------------------------------------------------
// Kernel 2: symmetric Gram tile (bf16-split MFMA) + count-sketch scatter
// grid = (136 tile pairs, 1, 8 batch), 256 threads (4 waves)
// LDS layout XOR-swizzle: elem(row,kgrp) at row*32 + (kgrp ^ ((row>>1)&3))*8
// -> fragment ds_read_b128 is bank-conflict-free (8 distinct bank groups per
//    8-lane phase), while each global_load_lds still stages 16 rows x 64B.
// ---------------------------------------------------------------------------
__device__ __forceinline__ void stage_tile(
    const unsigned short* __restrict__ src, size_t rowbase_elems,
    unsigned short* lds_tile, int wv, int lane, int k0)
{
#pragma unroll
    for (int half = 0; half < 2; ++half) {
        int ch  = wv * 2 + half;                       // 0..7 chunk of 8KB tile
        int row = ch * 16 + (lane >> 2);
        int kg  = (lane & 3) ^ ((lane >> 3) & 3);      // XOR swizzle (row>>1)&3
        const unsigned short* g = src + rowbase_elems
            + (size_t)row * KPAD + k0 + kg * 8;
        __builtin_amdgcn_global_load_lds(
            (__attribute__((address_space(1))) void*)g,
            (__attribute__((address_space(3))) void*)(lds_tile + ch * 512),
            16, 0, 0);
    }
}

__global__ __launch_bounds__(256) void gram_scatter_kernel(
    const unsigned short* __restrict__ xhi,
    const unsigned short* __restrict__ xlo,
    const int*   __restrict__ h1, const float* __restrict__ s1,
    const int*   __restrict__ h2, const float* __restrict__ s2,
    float* __restrict__ y)
{
    __shared__ __align__(16) unsigned short smA_hi[128 * 32];
    __shared__ __align__(16) unsigned short smA_lo[128 * 32];
    __shared__ __align__(16) unsigned short smB_hi[128 * 32];
    __shared__ __align__(16) unsigned short smB_lo[128 * 32];
    __shared__ float bins[DDIM];                       // 32 KB private histogram

    const int tid  = threadIdx.x;
    const int lane = tid & 63;
    const int wv   = tid >> 6;
    const int b    = blockIdx.z;

    // Triangular decode: blockIdx.x in [0,136) -> (tM, tN), tM <= tN
    int tM = 0, tN = 0;
    {
        int i = blockIdx.x;
#pragma unroll 1
        for (int t = 0; t < NTILE; ++t) {
            int cnt = NTILE - t;
            if (i < cnt) { tM = t; tN = t + i; break; }
            i -= cnt;
        }
    }
    const bool diag = (tM == tN);

    for (int i = tid; i < DDIM; i += 256) bins[i] = 0.0f;
    // (first __syncthreads inside k-loop orders this before any scatter)

    const int wrow = (wv >> 1) * 64;    // wave's 64x64 subtile origin
    const int wcol = (wv & 1) * 64;

    const size_t rowbaseA = ((size_t)b * CH + (size_t)tM * 128) * KPAD;
    const size_t rowbaseB = ((size_t)b * CH + (size_t)tN * 128) * KPAD;

    const unsigned short* fragBhi = diag ? smA_hi : smB_hi;
    const unsigned short* fragBlo = diag ? smA_lo : smB_lo;

    f32x4 acc[4][4];
    const f32x4 zv = {0.0f, 0.0f, 0.0f, 0.0f};
#pragma unroll
    for (int mi = 0; mi < 4; ++mi)
#pragma unroll
        for (int ni = 0; ni < 4; ++ni) acc[mi][ni] = zv;

    // fragment LDS offset: (wrow+i*16+(lane&15))*32 + fxor, where the XOR term
    // reduces to a per-lane constant since tile-row base is a multiple of 16
    const int fxor = (((lane >> 4) ^ ((lane >> 1) & 3)) << 3);
    const int rsel = lane & 15;

    for (int ks = 0; ks < KSTEPS; ++ks) {
        const int k0 = ks * 32;
        stage_tile(xhi, rowbaseA, smA_hi, wv, lane, k0);
        stage_tile(xlo, rowbaseA, smA_lo, wv, lane, k0);
        if (!diag) {
            stage_tile(xhi, rowbaseB, smB_hi, wv, lane, k0);
            stage_tile(xlo, rowbaseB, smB_lo, wv, lane, k0);
        }
        __syncthreads();

        bf16x8 ah[4], al[4], bh[4], bl[4];
#pragma unroll
        for (int i = 0; i < 4; ++i) {
            int offa = (wrow + i * 16 + rsel) * 32 + fxor;
            ah[i] = *(const bf16x8*)&smA_hi[offa];
            al[i] = *(const bf16x8*)&smA_lo[offa];
            int offb = (wcol + i * 16 + rsel) * 32 + fxor;
            bh[i] = *(const bf16x8*)&fragBhi[offb];
            bl[i] = *(const bf16x8*)&fragBlo[offb];
        }
#pragma unroll
        for (int mi = 0; mi < 4; ++mi)
#pragma unroll
            for (int ni = 0; ni < 4; ++ni) {
                acc[mi][ni] = __builtin_amdgcn_mfma_f32_16x16x32_bf16(ah[mi], bh[ni], acc[mi][ni], 0, 0, 0);
                acc[mi][ni] = __builtin_amdgcn_mfma_f32_16x16x32_bf16(ah[mi], bl[ni], acc[mi][ni], 0, 0, 0);
                acc[mi][ni] = __builtin_amdgcn_mfma_f32_16x16x32_bf16(al[mi], bh[ni], acc[mi][ni], 0, 0, 0);
            }
        __syncthreads();
    }

    // Scatter the 128x128 Gram tile into the LDS histogram.
    // C/D layout (m89-verified): col = lane&15, row = (lane>>4)*4 + reg
    // Off-diagonal pair: each entry contributes twice (G symmetric):
    //   (c1,c2): s1[c1]*s2[c2] -> bin h1[c1]+h2[c2]
    //   (c2,c1): s1[c2]*s2[c1] -> bin h1[c2]+h2[c1]
    const int c2b = tN * 128 + wcol + (lane & 15);
    const int c1b = tM * 128 + wrow + ((lane >> 4) << 2);
    int   h1c[4], h2c[4]; float s1c[4], s2c[4];
#pragma unroll
    for (int ni = 0; ni < 4; ++ni) {
        int c2 = c2b + ni * 16;
        h1c[ni] = h1[c2]; s1c[ni] = s1[c2];
        h2c[ni] = h2[c2]; s2c[ni] = s2[c2];
    }
#pragma unroll
    for (int mi = 0; mi < 4; ++mi) {
#pragma unroll
        for (int r = 0; r < 4; ++r) {
            const int c1 = c1b + mi * 16 + r;
            const int h1r = h1[c1]; const float s1r = s1[c1];
            const int h2r = h2[c1]; const float s2r = s2[c1];
#pragma unroll
            for (int ni = 0; ni < 4; ++ni) {
                float g = acc[mi][ni][r];
                atomicAdd(&bins[(h1r + h2c[ni]) & (DDIM - 1)], s1r * s2c[ni] * g);
                if (!diag)
                    atomicAdd(&bins[(h1c[ni] + h2r) & (DDIM - 1)], s1c[ni] * s2r * g);
            }
        }
    }

    __syncthreads();   // all scatters into bins complete
    float* yb = y + (size_t)b * DDIM;
    for (int i = tid; i < DDIM; i += 256) {
        float v = bins[i];
        if (v != 0.0f) atomicAdd(&yb[i], v);
    }
}

// ---------------------------------------------------------------------------
// Kernel 3: feat = sign(y)*sqrt(|y|) / max(||.||2, 1e-12)   (one block per b)
// Note sum(feat_unnorm^2) == sum(|y|).
// ---------------------------------------------------------------------------
__global__ __launch_bounds__(256) void feat_kernel(
    const float* __restrict__ y, float* __restrict__ out)
{
    const int b = blockIdx.x;
    const int tid = threadIdx.x;
    __shared__ float red[256];
    float ss = 0.0f;
    for (int i = tid; i < DDIM; i += 256) ss += fabsf(y[(size_t)b * DDIM + i]);
    red[tid] = ss;
    __syncthreads();
    for (int s = 128; s > 0; s >>= 1) {
        if (tid < s) red[tid] += red[tid + s];
        __syncthreads();
    }
    const float inv = 1.0f / fmaxf(sqrtf(red[0]), 1e-12f);
    for (int i = tid; i < DDIM; i += 256) {
        float v = y[(size_t)b * DDIM + i];
        float t = copysignf(sqrtf(fabsf(v)), v);
        out[BATCH * NCLS + (size_t)b * DDIM + i] = t * inv;
    }
}

// ---------------------------------------------------------------------------
// Kernel 4: logit[b,n] = feat[b,:] @ W[:,n] + b_cls[n]   (grid 200 x 8)
// ---------------------------------------------------------------------------
__global__ __launch_bounds__(256) void logit_kernel(
    const float* __restrict__ feat_base, const float* __restrict__ W,
    const float* __restrict__ bc, float* __restrict__ logit)
{
    const int n = blockIdx.x;
    const int b = blockIdx.y;
    const int tid = threadIdx.x;
    const float* feat = feat_base + (size_t)b * DDIM;
    float s = 0.0f;
    for (int d = tid; d < DDIM; d += 256) s += feat[d] * W[(size_t)d * NCLS + n];
    __shared__ float red[256];
    red[tid] = s;
    __syncthreads();
    for (int st = 128; st > 0; st >>= 1) {
        if (tid < st) red[tid] += red[tid + st];
        __syncthreads();
    }
    if (tid == 0) logit[(size_t)b * NCLS + n] = red[0] + bc[n];
}

// ---------------------------------------------------------------------------
extern "C" void kernel_launch(void* const* d_in, const int* in_sizes, int n_in,
                              void* d_out, int out_size, void* d_ws, size_t ws_size,
                              hipStream_t stream)
{
    const float* x  = (const float*)d_in[0];
    const float* s1 = (const float*)d_in[1];
    const float* s2 = (const float*)d_in[2];
    const float* W  = (const float*)d_in[3];
    const float* bc = (const float*)d_in[4];
    const int*   h1 = (const int*)d_in[5];
    const int*   h2 = (const int*)d_in[6];
    float* out = (float*)d_out;

    // workspace layout: y (256KB) | xhi (25MB) | xlo (25MB)  -> ~50.3 MB
    char* ws = (char*)d_ws;
    float* y = (float*)ws;
    const size_t ybytes = (size_t)BATCH * DDIM * sizeof(float);
    unsigned short* xhi = (unsigned short*)(ws + ybytes);
    unsigned short* xlo = (unsigned short*)(ws + ybytes + (size_t)BATCH * CH * KPAD * 2);

    hipMemsetAsync(y, 0, ybytes, stream);   // ws is re-poisoned before each call

    split_kernel<<<(BATCH * CH * KPAD / 4 + 255) / 256, 256, 0, stream>>>(x, xhi, xlo);

    dim3 grid_g(NPAIR, 1, BATCH);   // symmetric tile pairs, batch
    gram_scatter_kernel<<<grid_g, 256, 0, stream>>>(xhi, xlo, h1, s1, h2, s2, y);

    feat_kernel<<<BATCH, 256, 0, stream>>>(y, out);

    logit_kernel<<<dim3(NCLS, BATCH), 256, 0, stream>>>(out + BATCH * NCLS, W, bc, out);
}